// Round 3
// baseline (479.627 us; speedup 1.0000x reference)
//
#include <hip/hip_runtime.h>

#define A_COUNT 100000
#define B_COUNT 8
#define C_COUNT 80
#define T_COUNT 50
#define BLOCK   256
#define NF4     (C_COUNT / 4)          // 20 float4 per anchor row
#define IMG_F4  (A_COUNT * NF4)        // 2,000,000 float4 per image
#define GX_B    1024                   // blocks.x for streaming kernel
#define TPI     (GX_B * BLOCK)         // threads per image sweep = 262144
#define KB_IT   8                      // ceil(IMG_F4 / TPI)

typedef float f4v __attribute__((ext_vector_type(4)));

// ---------------------------------------------------------------------------
// Kernel A: anchor assignment. Per anchor: IoU argmax vs 50 targets,
// pos/neg/ignore decision, smooth-L1 reg loss for positives, positive-class
// focal fixup (so kernel B can treat every non-ignored anchor as pure
// negative), and a per-anchor focal weight (0.0 ignore / 0.75 otherwise)
// written to ws for kernel B.
// ---------------------------------------------------------------------------
__global__ __launch_bounds__(BLOCK) void retina_state(
    const float* __restrict__ clas,    // [B, A, C]
    const float* __restrict__ regs,    // [B, A, 4]
    const float* __restrict__ anchors, // [1, A, 4] corner form
    const float* __restrict__ targets, // [B, T, 5]
    float* __restrict__ ws_cls,        // [B]  (receives positive fixup part)
    float* __restrict__ ws_reg,        // [B]
    int*   __restrict__ ws_pos,        // [B]
    float* __restrict__ ws_w)          // [B*A] per-anchor focal weight
{
    __shared__ float s_tgt[T_COUNT * 5];
    __shared__ float s_c[4], s_r[4];
    __shared__ int   s_p[4];

    const int b    = blockIdx.y;
    const int base = blockIdx.x * BLOCK;
    const int tid  = threadIdx.x;

    for (int i = tid; i < T_COUNT * 5; i += BLOCK)
        s_tgt[i] = targets[b * T_COUNT * 5 + i];
    __syncthreads();

    const int a = base + tid;
    float my_reg = 0.0f;
    float my_fix = 0.0f;
    bool  my_pos = false;

    if (a < A_COUNT) {
        const float4 an = ((const float4*)anchors)[a];  // x1 y1 x2 y2
        const float area_a = (an.z - an.x) * (an.w - an.y);

        float best = -1.0f;
        int   bestIdx = 0;
        bool  anyValid = false;

        #pragma unroll 1
        for (int t = 0; t < T_COUNT; ++t) {
            const float tx1 = s_tgt[t * 5 + 0];
            const float ty1 = s_tgt[t * 5 + 1];
            const float tx2 = s_tgt[t * 5 + 2];
            const float ty2 = s_tgt[t * 5 + 3];
            const float lab = s_tgt[t * 5 + 4];
            float iou = -1.0f;
            if (lab != -1.0f) {
                anyValid = true;
                const float lx = fmaxf(an.x, tx1), ly = fmaxf(an.y, ty1);
                const float rx = fminf(an.z, tx2), ry = fminf(an.w, ty2);
                const float w = fmaxf(rx - lx, 0.0f);
                const float h = fmaxf(ry - ly, 0.0f);
                const float inter  = w * h;
                const float area_b = (tx2 - tx1) * (ty2 - ty1);
                iou = inter / (area_a + area_b - inter);
            }
            if (iou > best) { best = iou; bestIdx = t; }  // first-occurrence argmax
        }

        float wgt = 0.0f;   // ignore by default (also the !anyValid case)
        if (anyValid) {
            if (best >= 0.5f) {
                wgt    = 0.75f;
                my_pos = true;
                const int cls_id = (int)s_tgt[bestIdx * 5 + 4];

                // positive-class focal fixup:
                //  + alpha*(1-p)^2*(-log p)  (true positive term)
                //  - 0.75*p^2*(-log(1-p))    (remove negative-assumption term)
                float p = clas[((size_t)b * A_COUNT + a) * C_COUNT + cls_id];
                p = fminf(fmaxf(p, 1e-4f), 1.0f - 1e-4f);
                const float om = 1.0f - p;
                my_fix = 0.25f * om * om * (-__logf(p))
                       - 0.75f * p * p   * (-__logf(om));

                // smooth-L1 on encoded box vs regression output
                const float4 rg = ((const float4*)regs)[(size_t)b * A_COUNT + a];
                const float tx1 = s_tgt[bestIdx * 5 + 0];
                const float ty1 = s_tgt[bestIdx * 5 + 1];
                const float tx2 = s_tgt[bestIdx * 5 + 2];
                const float ty2 = s_tgt[bestIdx * 5 + 3];
                const float pcx = (an.x + an.z) * 0.5f, pcy = (an.y + an.w) * 0.5f;
                const float pw  = an.z - an.x,          ph  = an.w - an.y;
                const float mcx = (tx1 + tx2) * 0.5f,   mcy = (ty1 + ty2) * 0.5f;
                const float mw  = tx2 - tx1,            mh  = ty2 - ty1;
                const float e0 = (mcx - pcx) / (0.1f * pw);
                const float e1 = (mcy - pcy) / (0.1f * ph);
                const float e2 = __logf(mw / pw) * 5.0f;   // /0.2
                const float e3 = __logf(mh / ph) * 5.0f;
                const float d0 = fabsf(e0 - rg.x);
                const float d1 = fabsf(e1 - rg.y);
                const float d2 = fabsf(e2 - rg.z);
                const float d3 = fabsf(e3 - rg.w);
                const float th  = 1.0f / 9.0f;
                const float c59 = 0.5f / 9.0f;
                const float s0 = (d0 <= th) ? 4.5f * d0 * d0 : d0 - c59;
                const float s1 = (d1 <= th) ? 4.5f * d1 * d1 : d1 - c59;
                const float s2 = (d2 <= th) ? 4.5f * d2 * d2 : d2 - c59;
                const float s3 = (d3 <= th) ? 4.5f * d3 * d3 : d3 - c59;
                my_reg = s0 + s1 + s2 + s3;
            } else if (best < 0.4f) {
                wgt = 0.75f;    // pure negative
            }
            // 0.4 <= best < 0.5 -> wgt stays 0 (ignore)
        }
        ws_w[b * A_COUNT + a] = wgt;
    }

    // block reduction: fixup (f32), reg (f32), pos count (int)
    float r0 = my_fix, r1 = my_reg;
    const unsigned long long bal = __ballot(my_pos);
    const int posc = __popcll(bal);
    #pragma unroll
    for (int off = 32; off > 0; off >>= 1) {
        r0 += __shfl_down(r0, off);
        r1 += __shfl_down(r1, off);
    }
    const int wave = tid >> 6, lane = tid & 63;
    if (lane == 0) { s_c[wave] = r0; s_r[wave] = r1; s_p[wave] = posc; }
    __syncthreads();
    if (tid == 0) {
        float tc = 0.0f, tr = 0.0f; int tp = 0;
        #pragma unroll
        for (int w = 0; w < 4; ++w) { tc += s_c[w]; tr += s_r[w]; tp += s_p[w]; }
        if (tc != 0.0f) atomicAdd(&ws_cls[b], tc);
        if (tr != 0.0f) atomicAdd(&ws_reg[b], tr);
        if (tp != 0)    atomicAdd(&ws_pos[b], tp);
    }
}

// ---------------------------------------------------------------------------
// Kernel B: pure streaming focal reduce. Every non-ignored anchor treated as
// pure negative: term = w * p^2 * (-log(1-p)), w in {0, 0.75} from ws_w.
// Minimal registers, no LDS staging, 8 float4 loads in flight per thread.
// ---------------------------------------------------------------------------
__global__ __launch_bounds__(BLOCK) void retina_focal(
    const float* __restrict__ clas,    // [B, A, C]
    const float* __restrict__ ws_w,    // [B*A]
    float* __restrict__ ws_cls)        // [B]
{
    __shared__ float s_c[4];

    const int b   = blockIdx.y;
    const int tid = threadIdx.x;
    const int i0  = blockIdx.x * BLOCK + tid;          // [0, TPI)

    const f4v*   cl4 = (const f4v*)(clas + (size_t)b * A_COUNT * C_COUNT);
    const float* wgt = ws_w + b * A_COUNT;

    f4v  v[KB_IT];
    bool ok[KB_IT];
    #pragma unroll
    for (int k = 0; k < KB_IT; ++k) {
        const int i = i0 + k * TPI;
        ok[k] = (i < IMG_F4);
        if (ok[k]) v[k] = cl4[i];
    }

    float acc = 0.0f;
    #pragma unroll
    for (int k = 0; k < KB_IT; ++k) {
        if (!ok[k]) continue;
        const int i = i0 + k * TPI;
        const float w = wgt[i / 20];                   // compiler magic-mul div
        #pragma unroll
        for (int j = 0; j < 4; ++j) {
            float p = fminf(fmaxf(v[k][j], 1e-4f), 1.0f - 1e-4f);
            float l = __logf(1.0f - p);                // < 0
            acc = fmaf(p * p * l, -w, acc);
        }
    }

    // block reduction -> one atomic
    #pragma unroll
    for (int off = 32; off > 0; off >>= 1)
        acc += __shfl_down(acc, off);
    const int wave = tid >> 6, lane = tid & 63;
    if (lane == 0) s_c[wave] = acc;
    __syncthreads();
    if (tid == 0) {
        float tc = s_c[0] + s_c[1] + s_c[2] + s_c[3];
        atomicAdd(&ws_cls[b], tc);
    }
}

__global__ void retina_final(const float* __restrict__ ws_cls,
                             const float* __restrict__ ws_reg,
                             const int*   __restrict__ ws_pos,
                             float* __restrict__ out)
{
    const int tid = threadIdx.x;
    float cl = 0.0f, rl = 0.0f;
    if (tid < B_COUNT) {
        const int   npi = ws_pos[tid];
        const float np  = (float)npi;
        cl = ws_cls[tid] / fmaxf(np, 1.0f);
        rl = (npi > 0) ? ws_reg[tid] / (np * 4.0f) : 0.0f;
    }
    #pragma unroll
    for (int off = 4; off > 0; off >>= 1) {
        cl += __shfl_down(cl, off);
        rl += __shfl_down(rl, off);
    }
    if (tid == 0) {
        out[0] = cl * (1.0f / (float)B_COUNT);
        out[1] = rl * (1.0f / (float)B_COUNT);
    }
}

extern "C" void kernel_launch(void* const* d_in, const int* in_sizes, int n_in,
                              void* d_out, int out_size, void* d_ws, size_t ws_size,
                              hipStream_t stream) {
    const float* clas    = (const float*)d_in[0];
    const float* regs    = (const float*)d_in[1];
    const float* anchors = (const float*)d_in[2];
    const float* targets = (const float*)d_in[3];

    float* ws_cls = (float*)d_ws;            // [8]
    float* ws_reg = ws_cls + B_COUNT;        // [8]
    int*   ws_pos = (int*)(ws_reg + B_COUNT);// [8]
    float* ws_w   = (float*)d_ws + 32;       // [B*A] weights (128 B offset)

    hipMemsetAsync(d_ws, 0, 32 * sizeof(float), stream);

    dim3 gridA((A_COUNT + BLOCK - 1) / BLOCK, B_COUNT);
    retina_state<<<gridA, BLOCK, 0, stream>>>(clas, regs, anchors, targets,
                                              ws_cls, ws_reg, ws_pos, ws_w);

    dim3 gridB(GX_B, B_COUNT);
    retina_focal<<<gridB, BLOCK, 0, stream>>>(clas, ws_w, ws_cls);

    retina_final<<<1, 64, 0, stream>>>(ws_cls, ws_reg, ws_pos, (float*)d_out);
}